// Round 15
// baseline (43.501 us; speedup 1.0000x reference)
//
#include <hip/hip_runtime.h>
#include <math.h>

// Problem constants (match reference setup_inputs)
#define NN 2048
#define LL 16
#define EPSF 1e-10f           // f32-rounded eps (reference's f32 clip)

static constexpr int TNT  = 6;               // neg-tile slots (256 wide) per label
static constexpr int TPC  = 10;              // pos-chunk slots (128 wide) per label
static constexpr int SLOT = TNT * TPC;       // 60 slots per label
static constexpr int GRP  = 4;               // tile-groups per block (1024 threads)
static constexpr int BPL  = SLOT / GRP;      // 15 blocks per label
static constexpr int NBLK = LL * BPL;        // 240 blocks total
static constexpr float LOG2E = 1.44269504088896340736f;
static constexpr unsigned MAGIC = 0x5EED5EEDu;   // != 0xAAAAAAAA poison

// ws layout:
//   [0    , 1920 ): double partial[240]
//   [1920 , 2048 ): double corr[16]
//   [2048 , 17408): unsigned flags[240] PADDED one per 64B line (stride 16 u32)

__global__ __launch_bounds__(1024) void fused_kernel(
    const float* __restrict__ inp, const float* __restrict__ tgt,
    const float* __restrict__ lw,
    double* __restrict__ partial, double* __restrict__ corr,
    unsigned* __restrict__ flags, float* __restrict__ out)
{
    const int gid = blockIdx.x;
    const int L   = gid / BPL;           // label
    const int rem = gid % BPL;           // block-within-label (4 slots each)
    const int tid = threadIdx.x;
    const int lane = tid & 63, wid = tid >> 6;   // wid in [0,16)

    __shared__ float posL[NN];           // 8 KB (scaled by log2e)
    __shared__ float negL[NN];           // 8 KB (scaled by log2e)
    __shared__ unsigned wco[16];
    __shared__ double red[16];
    __shared__ int okgate;

    // ---- gather: 2 rows of column L per thread (each row = one 64B line) ----
    const int r0 = tid * 2;
    const float s0 = inp[(size_t)r0 * LL + L];
    const float s1 = inp[(size_t)(r0 + 1) * LL + L];
    const int tg0 = (tgt[(size_t)r0 * LL + L] != 0.0f) ? 1 : 0;
    const int tg1 = (tgt[(size_t)(r0 + 1) * LL + L] != 0.0f) ? 1 : 0;

    // ---- int-only packed inclusive wave scan (pos | neg<<16) ----
    const int lpos = tg0 + tg1, lneg = 2 - lpos;
    const unsigned pk = (unsigned)lpos | ((unsigned)lneg << 16);
    unsigned ipk = pk;
#pragma unroll
    for (int off = 1; off < 64; off <<= 1) {
        const unsigned tu = __shfl_up(ipk, off, 64);
        if (lane >= off) ipk += tu;
    }
    if (lane == 63) wco[wid] = ipk;
    __syncthreads();

    unsigned basec = 0;
    for (int w = 0; w < wid; ++w) basec += wco[w];
    unsigned totc = 0;
#pragma unroll
    for (int w = 0; w < 16; ++w) totc += wco[w];
    const int npos = (int)(totc & 0xffffu);
    const int nneg = (int)(totc >> 16);
    const int nchunkP = (npos + 127) >> 7;       // active pos chunks
    const int ntileN  = (nneg + 255) >> 8;       // active neg tiles

    // this block's 4 slots; fully-ghost blocks skip compute (rem==0: corr)
    const int grp  = tid >> 8;                   // 0..3 tile-group
    const int slot = rem * GRP + grp;            // 0..59
    const int nt = slot / TPC, pc = slot % TPC;
    const bool myvalid = (nt < ntileN) && (pc < nchunkP);
    bool anyv = false;
    {
        const int s0v = rem * GRP;
#pragma unroll
        for (int g = 0; g < GRP; ++g) {
            const int sl = s0v + g;
            anyv = anyv || ((sl / TPC) < ntileN && (sl % TPC) < nchunkP);
        }
    }
    const bool skipwork = (!anyv && rem != 0);   // block-uniform

    double acc = 0.0;
    if (!skipwork) {
        const unsigned exc = basec + ipk - pk;       // exclusive prefix
        int rp = (int)(exc & 0xffffu);
        int rn = (int)(exc >> 16);

        // ---- scatter (pre-scaled) + closed-form eps-corr (rem==0 only) ----
        const bool docorr = (rem == 0);
        double cl = 0.0;
        if (tg0) { posL[rp] = s0 * LOG2E; if (docorr) cl += (double)rn * (double)s0; ++rp; }
        else     { negL[rn] = s0 * LOG2E; if (docorr) cl -= (double)(npos - rp) * (double)s0; ++rn; }
        if (tg1) { posL[rp] = s1 * LOG2E; if (docorr) cl += (double)rn * (double)s1; ++rp; }
        else     { negL[rn] = s1 * LOG2E; if (docorr) cl -= (double)(npos - rp) * (double)s1; ++rn; }

        if (docorr) {
#pragma unroll
            for (int off = 32; off > 0; off >>= 1)
                cl += __shfl_down(cl, off, 64);
            if (lane == 0) red[wid] = cl;
        }

        // pads: contribute exactly 0 (factor 1+exp2(-huge) = 1)
        const int posP = (npos + 127) & ~127;
        const int negP = (nneg + 255) & ~255;
        for (int idx = npos + tid; idx < posP; idx += 1024) posL[idx] =  1e30f;
        for (int idx = nneg + tid; idx < negP; idx += 1024) negL[idx] = -1e30f;
        __syncthreads();

        if (docorr && tid == 0) {
            double c = 0.0;
#pragma unroll
            for (int w = 0; w < 16; ++w) c += red[w];
            corr[L] = c;
        }
        if (docorr) __syncthreads();   // red[] reused below for acc reduce

        // ---- bipartite tile from LDS: 4-term product softplus (log2 domain) ----
        const int t256 = tid & 255;
        if (myvalid) {
            const float nv = negL[nt * 256 + t256];       // per-lane, conflict-free
            const float4* p4 = (const float4*)(posL + pc * 128);
#pragma unroll
            for (int r = 0; r < 32; ++r) {                // 128 pos values
                const float4 pv = p4[r];                  // uniform LDS broadcast
                const float e0 = __builtin_amdgcn_exp2f(nv - pv.x);
                const float e1 = __builtin_amdgcn_exp2f(nv - pv.y);
                const float e2 = __builtin_amdgcn_exp2f(nv - pv.z);
                const float e3 = __builtin_amdgcn_exp2f(nv - pv.w);
                const float P = ((1.0f + e0) * (1.0f + e1)) * ((1.0f + e2) * (1.0f + e3));
                acc += (double)__log2f(P);
            }
        }
    }

    // ---- block-wide f64 reduce (16 waves; ghosts contribute exact zeros) ----
#pragma unroll
    for (int off = 32; off > 0; off >>= 1)
        acc += __shfl_down(acc, off, 64);
    if (lane == 0) red[wid] = acc;
    __syncthreads();
    if (tid == 0) {
        double a = 0.0;
#pragma unroll
        for (int w = 0; w < 16; ++w) a += red[w];
        partial[gid] = a;
    }

    // ==== completion protocol: padded per-block flags, no shared-line RMW ====
    if (tid == 0) {
        // release: flush partial/corr to LLC, then commit own flag line
        __hip_atomic_store(&flags[(size_t)gid * 16], MAGIC,
                           __ATOMIC_RELEASE, __HIP_MEMORY_SCOPE_AGENT);
        __threadfence();               // vmcnt-ack: own store committed before sweep
    }
    __syncthreads();

    // parallel sweep: 240 threads read 240 independent lines (no exclusives)
    int ok = 1;
    if (tid < NBLK)
        ok = (__hip_atomic_load(&flags[(size_t)tid * 16],
                                __ATOMIC_RELAXED, __HIP_MEMORY_SCOPE_AGENT) == MAGIC);
    ok = __all(ok) ? 1 : 0;
    if (lane == 0) wco[wid] = (unsigned)ok;   // reuse wco as ok-gate storage
    __syncthreads();
    if (tid == 0) {
        unsigned A = 1;
#pragma unroll
        for (int w = 0; w < 16; ++w) A &= wco[w];
        okgate = (int)A;
    }
    __syncthreads();
    if (!okgate) return;               // not last: exit (no waiting, no deadlock)

    // ---- completer(s): acquire, then bit-identical R14 final reduce ----
    __threadfence();                   // invalidate L1/L2 -> read partials from LLC
    if (tid >= 256) return;            // exited waves release barriers on AMD

    const double LN2 = 0.69314718055994530942;
    double f = 0.0;
    if (tid < NBLK)
        f = (double)lw[tid / BPL] * (LN2 * partial[tid]);
    if (tid < LL)
        f += (double)lw[tid] * ((double)EPSF * corr[tid]);

#pragma unroll
    for (int off = 32; off > 0; off >>= 1)
        f += __shfl_down(f, off, 64);
    if (lane == 0) red[wid] = f;       // wid in [0,4)
    __syncthreads();
    if (tid == 0)
        out[0] = (float)(((((red[0] + red[1]) + red[2]) + red[3])) / (double)LL);

    // reset flags for the next replay (idempotent across multiple completers)
    if (tid < NBLK)
        __hip_atomic_store(&flags[(size_t)tid * 16], 0u,
                           __ATOMIC_RELAXED, __HIP_MEMORY_SCOPE_AGENT);
}

extern "C" void kernel_launch(void* const* d_in, const int* in_sizes, int n_in,
                              void* d_out, int out_size, void* d_ws, size_t ws_size,
                              hipStream_t stream) {
    const float* inp = (const float*)d_in[0];   // [2048, 16] f32
    const float* tgt = (const float*)d_in[1];   // [2048, 16] f32
    const float* lw  = (const float*)d_in[2];   // [16] f32
    float* out = (float*)d_out;

    char* ws = (char*)d_ws;
    double*   partial = (double*)(ws);          // 1920 B
    double*   corr    = (double*)(ws + 1920);   // 128 B
    unsigned* flags   = (unsigned*)(ws + 2048); // 240 x 64B-padded = 15360 B

    fused_kernel<<<NBLK, 1024, 0, stream>>>(inp, tgt, lw, partial, corr, flags, out);
}

// Round 16
// 16.687 us; speedup vs baseline: 2.6068x; 2.6068x over previous
//
#include <hip/hip_runtime.h>
#include <math.h>

// Problem constants (match reference setup_inputs)
#define NN 2048
#define LL 16
#define EPSF 1e-10f           // f32-rounded eps (reference's f32 clip)

static constexpr int TNT  = 6;               // neg-tile slots (256 wide) per label
static constexpr int TPC  = 10;              // pos-chunk slots (128 wide) per label
static constexpr int SLOT = TNT * TPC;       // 60 slots per label
static constexpr int GRP  = 4;               // tile-groups per block (1024 threads)
static constexpr int BPL  = SLOT / GRP;      // 15 blocks per label
static constexpr int NBLK = LL * BPL;        // 240 blocks total
static constexpr float LOG2E = 1.44269504088896340736f;

// ws layout: [0, 1920): double partial[240]; [1920, 2048): double corr[16]

__global__ __launch_bounds__(1024) void fused_kernel(
    const float* __restrict__ inp, const float* __restrict__ tgt,
    double* __restrict__ partial, double* __restrict__ corr)
{
    const int gid = blockIdx.x;
    const int L   = gid / BPL;           // label
    const int rem = gid % BPL;           // block-within-label (4 slots each)
    const int tid = threadIdx.x;
    const int lane = tid & 63, wid = tid >> 6;   // wid in [0,16)

    __shared__ float posL[NN];           // 8 KB (scaled by log2e)
    __shared__ float negL[NN];           // 8 KB (scaled by log2e)
    __shared__ unsigned wco[16];
    __shared__ double red[16];

    // ---- gather: 2 rows of column L per thread (each row = one 64B line) ----
    const int r0 = tid * 2;
    const float s0 = inp[(size_t)r0 * LL + L];
    const float s1 = inp[(size_t)(r0 + 1) * LL + L];
    const int tg0 = (tgt[(size_t)r0 * LL + L] != 0.0f) ? 1 : 0;
    const int tg1 = (tgt[(size_t)(r0 + 1) * LL + L] != 0.0f) ? 1 : 0;

    // ---- int-only packed inclusive wave scan (pos | neg<<16) ----
    const int lpos = tg0 + tg1, lneg = 2 - lpos;
    const unsigned pk = (unsigned)lpos | ((unsigned)lneg << 16);
    unsigned ipk = pk;
#pragma unroll
    for (int off = 1; off < 64; off <<= 1) {
        const unsigned tu = __shfl_up(ipk, off, 64);
        if (lane >= off) ipk += tu;
    }
    if (lane == 63) wco[wid] = ipk;
    __syncthreads();

    unsigned basec = 0;
    for (int w = 0; w < wid; ++w) basec += wco[w];
    unsigned totc = 0;
#pragma unroll
    for (int w = 0; w < 16; ++w) totc += wco[w];
    const int npos = (int)(totc & 0xffffu);
    const int nneg = (int)(totc >> 16);
    const int nchunkP = (npos + 127) >> 7;       // active pos chunks
    const int ntileN  = (nneg + 255) >> 8;       // active neg tiles

    // this block's 4 slots; fully-ghost blocks exit after scan (rem==0: corr)
    const int grp  = tid >> 8;                   // 0..3 tile-group
    const int slot = rem * GRP + grp;            // 0..59
    const int nt = slot / TPC, pc = slot % TPC;
    const bool myvalid = (nt < ntileN) && (pc < nchunkP);
    {
        const int s0v = rem * GRP;
        bool anyv = false;
#pragma unroll
        for (int g = 0; g < GRP; ++g) {
            const int sl = s0v + g;
            anyv = anyv || ((sl / TPC) < ntileN && (sl % TPC) < nchunkP);
        }
        if (!anyv && rem != 0) {
            if (tid == 0) partial[gid] = 0.0;
            return;
        }
    }

    const unsigned exc = basec + ipk - pk;       // exclusive prefix
    int rp = (int)(exc & 0xffffu);
    int rn = (int)(exc >> 16);

    // ---- scatter (pre-scaled) + closed-form eps-corr (rem==0 only) ----
    const bool docorr = (rem == 0);
    double cl = 0.0;
    if (tg0) { posL[rp] = s0 * LOG2E; if (docorr) cl += (double)rn * (double)s0; ++rp; }
    else     { negL[rn] = s0 * LOG2E; if (docorr) cl -= (double)(npos - rp) * (double)s0; ++rn; }
    if (tg1) { posL[rp] = s1 * LOG2E; if (docorr) cl += (double)rn * (double)s1; ++rp; }
    else     { negL[rn] = s1 * LOG2E; if (docorr) cl -= (double)(npos - rp) * (double)s1; ++rn; }

    if (docorr) {
#pragma unroll
        for (int off = 32; off > 0; off >>= 1)
            cl += __shfl_down(cl, off, 64);
        if (lane == 0) red[wid] = cl;
    }

    // pads: contribute exactly 0 (factor 1+exp2(-huge) = 1)
    const int posP = (npos + 127) & ~127;
    const int negP = (nneg + 255) & ~255;
    for (int idx = npos + tid; idx < posP; idx += 1024) posL[idx] =  1e30f;
    for (int idx = nneg + tid; idx < negP; idx += 1024) negL[idx] = -1e30f;
    __syncthreads();

    if (docorr && tid == 0) {
        double c = 0.0;
#pragma unroll
        for (int w = 0; w < 16; ++w) c += red[w];
        corr[L] = c;
    }
    if (docorr) __syncthreads();   // red[] reused below for acc reduce

    // ---- bipartite tile from LDS: 4-term product softplus (log2 domain) ----
    const int t256 = tid & 255;
    double acc = 0.0;
    if (myvalid) {
        const float nv = negL[nt * 256 + t256];       // per-lane, conflict-free
        const float4* p4 = (const float4*)(posL + pc * 128);
#pragma unroll
        for (int r = 0; r < 32; ++r) {                // 128 pos values
            const float4 pv = p4[r];                  // uniform LDS broadcast
            const float e0 = __builtin_amdgcn_exp2f(nv - pv.x);
            const float e1 = __builtin_amdgcn_exp2f(nv - pv.y);
            const float e2 = __builtin_amdgcn_exp2f(nv - pv.z);
            const float e3 = __builtin_amdgcn_exp2f(nv - pv.w);
            const float P = ((1.0f + e0) * (1.0f + e1)) * ((1.0f + e2) * (1.0f + e3));
            acc += (double)__log2f(P);
        }
    }

    // ---- block-wide f64 reduce (16 waves, deterministic order) ----
#pragma unroll
    for (int off = 32; off > 0; off >>= 1)
        acc += __shfl_down(acc, off, 64);
    if (lane == 0) red[wid] = acc;
    __syncthreads();
    if (tid == 0) {
        double a = 0.0;
#pragma unroll
        for (int w = 0; w < 16; ++w) a += red[w];
        partial[gid] = a;
    }
}

// ---- weighted final reduce ----
__global__ __launch_bounds__(256) void final_kernel(
    const double* __restrict__ partial, const double* __restrict__ corr,
    const float* __restrict__ lw, float* __restrict__ out)
{
    const int tid = threadIdx.x;
    const double LN2 = 0.69314718055994530942;

    double acc = 0.0;
    if (tid < NBLK)
        acc = (double)lw[tid / BPL] * (LN2 * partial[tid]);
    if (tid < LL)
        acc += (double)lw[tid] * ((double)EPSF * corr[tid]);

    const int lane = tid & 63, wid = tid >> 6;
#pragma unroll
    for (int off = 32; off > 0; off >>= 1)
        acc += __shfl_down(acc, off, 64);
    __shared__ double smem[4];
    if (lane == 0) smem[wid] = acc;
    __syncthreads();
    if (tid == 0)
        out[0] = (float)((smem[0] + smem[1] + smem[2] + smem[3]) / (double)LL);
}

extern "C" void kernel_launch(void* const* d_in, const int* in_sizes, int n_in,
                              void* d_out, int out_size, void* d_ws, size_t ws_size,
                              hipStream_t stream) {
    const float* inp = (const float*)d_in[0];   // [2048, 16] f32
    const float* tgt = (const float*)d_in[1];   // [2048, 16] f32
    const float* lw  = (const float*)d_in[2];   // [16] f32
    float* out = (float*)d_out;

    char* ws = (char*)d_ws;
    double* partial = (double*)(ws);            // 1920 B
    double* corr    = (double*)(ws + 1920);     // 128 B

    fused_kernel<<<NBLK, 1024, 0, stream>>>(inp, tgt, partial, corr);
    final_kernel<<<1, 256, 0, stream>>>(partial, corr, lw, out);
}

// Round 17
// 16.650 us; speedup vs baseline: 2.6127x; 1.0023x over previous
//
#include <hip/hip_runtime.h>
#include <math.h>

// Problem constants (match reference setup_inputs)
#define NN 2048
#define LL 16
#define EPSF 1e-10f           // f32-rounded eps (reference's f32 clip)

static constexpr int GRP  = 4;               // valid-slots per block (1024 threads)
static constexpr int BPL  = 11;              // blocks per label (covers 44 >= 40 worst-case valid slots)
static constexpr int NBLK = LL * BPL;        // 176 blocks total
static constexpr float LOG2E = 1.44269504088896340736f;

// ws layout: [0, 1408): double partial[176]; [1536, 1664): double corr[16]

__global__ __launch_bounds__(1024) void fused_kernel(
    const float* __restrict__ inp, const float* __restrict__ tgt,
    double* __restrict__ partial, double* __restrict__ corr)
{
    const int gid = blockIdx.x;
    const int L   = gid / BPL;           // label
    const int rem = gid % BPL;           // block-within-label (4 valid-slots each)
    const int tid = threadIdx.x;
    const int lane = tid & 63, wid = tid >> 6;   // wid in [0,16)

    __shared__ float posL[NN];           // 8 KB (scaled by log2e)
    __shared__ float negL[NN];           // 8 KB (scaled by log2e)
    __shared__ unsigned wco[16];
    __shared__ double red[16];

    // ---- gather: 2 rows of column L per thread (each row = one 64B line) ----
    const int r0 = tid * 2;
    const float s0 = inp[(size_t)r0 * LL + L];
    const float s1 = inp[(size_t)(r0 + 1) * LL + L];
    const int tg0 = (tgt[(size_t)r0 * LL + L] != 0.0f) ? 1 : 0;
    const int tg1 = (tgt[(size_t)(r0 + 1) * LL + L] != 0.0f) ? 1 : 0;

    // ---- int-only packed inclusive wave scan (pos | neg<<16) ----
    const int lpos = tg0 + tg1, lneg = 2 - lpos;
    const unsigned pk = (unsigned)lpos | ((unsigned)lneg << 16);
    unsigned ipk = pk;
#pragma unroll
    for (int off = 1; off < 64; off <<= 1) {
        const unsigned tu = __shfl_up(ipk, off, 64);
        if (lane >= off) ipk += tu;
    }
    if (lane == 63) wco[wid] = ipk;
    __syncthreads();

    unsigned basec = 0;
    for (int w = 0; w < wid; ++w) basec += wco[w];
    unsigned totc = 0;
#pragma unroll
    for (int w = 0; w < 16; ++w) totc += wco[w];
    const int npos = (int)(totc & 0xffffu);
    const int nneg = (int)(totc >> 16);
    const int nchunkP = (npos + 127) >> 7;       // active pos chunks
    const int ntileN  = (nneg + 255) >> 8;       // active neg tiles
    const int vcount  = ntileN * nchunkP;        // dense valid-slot count (<= 40 proven)

    // this block's 4 valid-slots: v in [rem*4, rem*4+4) of the dense enumeration
    const int v0 = rem * GRP;
    if (rem != 0 && v0 >= vcount) {              // fully-ghost: exit after scan
        if (tid == 0) partial[gid] = 0.0;
        return;
    }
    const int grp = tid >> 8;                    // 0..3 tile-group
    const int v   = v0 + grp;
    const bool myvalid = (v < vcount);
    int nt = 0, pc = 0;
    if (myvalid) { nt = v / nchunkP; pc = v % nchunkP; }

    const unsigned exc = basec + ipk - pk;       // exclusive prefix
    int rp = (int)(exc & 0xffffu);
    int rn = (int)(exc >> 16);

    // ---- scatter (pre-scaled) + closed-form eps-corr (rem==0 only) ----
    const bool docorr = (rem == 0);
    double cl = 0.0;
    if (tg0) { posL[rp] = s0 * LOG2E; if (docorr) cl += (double)rn * (double)s0; ++rp; }
    else     { negL[rn] = s0 * LOG2E; if (docorr) cl -= (double)(npos - rp) * (double)s0; ++rn; }
    if (tg1) { posL[rp] = s1 * LOG2E; if (docorr) cl += (double)rn * (double)s1; ++rp; }
    else     { negL[rn] = s1 * LOG2E; if (docorr) cl -= (double)(npos - rp) * (double)s1; ++rn; }

    if (docorr) {
#pragma unroll
        for (int off = 32; off > 0; off >>= 1)
            cl += __shfl_down(cl, off, 64);
        if (lane == 0) red[wid] = cl;
    }

    // pads: contribute exactly 0 (factor 1+exp2(-huge) = 1)
    const int posP = (npos + 127) & ~127;
    const int negP = (nneg + 255) & ~255;
    for (int idx = npos + tid; idx < posP; idx += 1024) posL[idx] =  1e30f;
    for (int idx = nneg + tid; idx < negP; idx += 1024) negL[idx] = -1e30f;
    __syncthreads();

    if (docorr && tid == 0) {
        double c = 0.0;
#pragma unroll
        for (int w = 0; w < 16; ++w) c += red[w];
        corr[L] = c;
    }
    if (docorr) __syncthreads();   // red[] reused below for acc reduce

    // ---- bipartite tile from LDS: 4-term product softplus (log2 domain) ----
    const int t256 = tid & 255;
    double acc = 0.0;
    if (myvalid) {
        const float nv = negL[nt * 256 + t256];       // per-lane, conflict-free
        const float4* p4 = (const float4*)(posL + pc * 128);
#pragma unroll
        for (int r = 0; r < 32; ++r) {                // 128 pos values
            const float4 pv = p4[r];                  // uniform LDS broadcast
            const float e0 = __builtin_amdgcn_exp2f(nv - pv.x);
            const float e1 = __builtin_amdgcn_exp2f(nv - pv.y);
            const float e2 = __builtin_amdgcn_exp2f(nv - pv.z);
            const float e3 = __builtin_amdgcn_exp2f(nv - pv.w);
            const float P = ((1.0f + e0) * (1.0f + e1)) * ((1.0f + e2) * (1.0f + e3));
            acc += (double)__log2f(P);
        }
    }

    // ---- block-wide f64 reduce (16 waves, deterministic order) ----
#pragma unroll
    for (int off = 32; off > 0; off >>= 1)
        acc += __shfl_down(acc, off, 64);
    if (lane == 0) red[wid] = acc;
    __syncthreads();
    if (tid == 0) {
        double a = 0.0;
#pragma unroll
        for (int w = 0; w < 16; ++w) a += red[w];
        partial[gid] = a;
    }
}

// ---- weighted final reduce: one wave, pure shuffle (no LDS/barriers) -------
__global__ __launch_bounds__(64) void final_kernel(
    const double* __restrict__ partial, const double* __restrict__ corr,
    const float* __restrict__ lw, float* __restrict__ out)
{
    const int t = threadIdx.x;                   // 0..63
    const double LN2 = 0.69314718055994530942;

    double acc = (double)lw[t / BPL] * (LN2 * partial[t]);
    {
        const int i = 64 + t;                    // 64..127
        acc += (double)lw[i / BPL] * (LN2 * partial[i]);
    }
    if (t < NBLK - 128) {                        // 128..175
        const int i = 128 + t;
        acc += (double)lw[i / BPL] * (LN2 * partial[i]);
    }
    if (t < LL)
        acc += (double)lw[t] * ((double)EPSF * corr[t]);

#pragma unroll
    for (int off = 32; off > 0; off >>= 1)
        acc += __shfl_down(acc, off, 64);
    if (t == 0)
        out[0] = (float)(acc / (double)LL);
}

extern "C" void kernel_launch(void* const* d_in, const int* in_sizes, int n_in,
                              void* d_out, int out_size, void* d_ws, size_t ws_size,
                              hipStream_t stream) {
    const float* inp = (const float*)d_in[0];   // [2048, 16] f32
    const float* tgt = (const float*)d_in[1];   // [2048, 16] f32
    const float* lw  = (const float*)d_in[2];   // [16] f32
    float* out = (float*)d_out;

    char* ws = (char*)d_ws;
    double* partial = (double*)(ws);            // 1408 B
    double* corr    = (double*)(ws + 1536);     // 128 B

    fused_kernel<<<NBLK, 1024, 0, stream>>>(inp, tgt, partial, corr);
    final_kernel<<<1, 64, 0, stream>>>(partial, corr, lw, out);
}